// Round 12
// baseline (75.443 us; speedup 1.0000x reference)
//
#include <hip/hip_runtime.h>
#include <cstdint>
#include <cstddef>

#define BB 16
#define NTOT 1048576
#define SS 32
#define SEG 32768
#define DIM 256
#define VW 512        // verifier bitmap words (16384 bits)

// ---------------- workspace layout (bytes), sizes derived explicitly ----------
// histX : BB*SS*256*4 = 524,288      [0, 524288)
// histY : 524,288                    [524288, 1048576)   dead after k_shifts
// BM0   : 16*8segs*2parts*512*4 = 524,288  [1048576, 1572864)
// STG   : BB*2halves*16384 u32 = 2,097,152 [2138112, 4235264) packed-u16 image
#define OFF_HX   0u
#define OFF_HY   524288u
#define OFF_BM0  1048576u
#define OFF_AX   2097152u            // BB*SS*4 = 2048
#define OFF_AY   2099200u            // 2048
#define OFF_PR   2101248u            // 2048
#define OFF_ACT  2103296u            // 1024
#define OFF_TOT  2104320u            // 1024
#define OFF_VER  2105344u            // BB*VW*4 = 32768
#define OFF_STG  2138112u            // 2 MB -> end 4,235,264 (~4.04 MB)

__device__ __forceinline__ int clamp255(int v) {
    return v < 0 ? 0 : (v > 255 ? 255 : v);
}

// ---------------- K1: 2D u8 pair-count image -> 1D hists (HALF the scatter ops)
// grid = BB*SS = 512 blocks x 512 thr, 64KB+2KB LDS -> 2 blocks/CU, 16 w/CU.
// One atomicAdd counts an (x,y) PAIR (u8 byte in u32 word): 16.8M updates vs
// 33.5M for separate 1D hists — the ~50cy/wave-scatter wall (rounds 4-10) is
// per UPDATE, so this halves the hist wall. histX = column sums, histY = row
// sums of the image (exact integer, packed-u16 reductions, conflict-free).
// u8 cell max ~10 on uniform data (lambda=0.5/cell) — no byte carry.
// Also pre-zeros the accum staging buffer (1024 words per block).
__global__ __launch_bounds__(512) void k_img(const int* __restrict__ xs,
                                             const int* __restrict__ ys,
                                             uint32_t* __restrict__ histX,
                                             uint32_t* __restrict__ histY,
                                             uint32_t* __restrict__ staging) {
    int blk = blockIdx.x;             // b*32 + s
    int s = blk & 31, b = blk >> 5;
    int t = threadIdx.x;
    // zero staging: 512 blocks x 1024 words = 2 MB
    {
        uint32_t* stg = staging + (size_t)blk * 1024;
        stg[t] = 0u; stg[t + 512] = 0u;
    }

    __shared__ uint32_t img[16384];           // 256x256 u8 cells = 64 KB
    __shared__ uint32_t xpart[4][64][2];      // histX per-wave packed partials
#pragma unroll
    for (int i = 0; i < 32; ++i) img[t + i * 512] = 0u;
    __syncthreads();

    size_t base = (size_t)b * NTOT + (size_t)s * SEG;
    const int4* x4 = (const int4*)(xs + base);
    const int4* y4 = (const int4*)(ys + base);
#pragma unroll 4
    for (int i = 0; i < 16; ++i) {            // 16 * 512 * 4 = 32768 pairs
        int4 xv = x4[i * 512 + t];
        int4 yv = y4[i * 512 + t];
#define DOI(xc, yc) { int cell = (xc) | ((yc) << 8); \
                      atomicAdd(&img[cell >> 2], 1u << ((cell & 3) << 3)); }
        DOI(xv.x, yv.x) DOI(xv.y, yv.y) DOI(xv.z, yv.z) DOI(xv.w, yv.w)
#undef DOI
    }
    __syncthreads();

    int wv = t >> 6, lane = t & 63;
    if (t < 256) {
        // histX: wave wv sums y in [wv*64,(wv+1)*64); lane owns word-column
        // `lane` (x = 4*lane+byte). word idx = lane + 64y -> bank lane%32 (free).
        uint32_t s02 = 0u, s13 = 0u;
        int y0 = wv << 6;
        for (int y = y0; y < y0 + 64; ++y) {
            uint32_t w = img[lane + (y << 6)];
            s02 += w & 0x00FF00FFu;
            s13 += (w >> 8) & 0x00FF00FFu;
        }
        xpart[wv][lane][0] = s02;
        xpart[wv][lane][1] = s13;
    } else {
        // histY: thread owns row y = t-256; words 64y+jj, jj rotated by lane
        // -> bank (j+lane)%32 (free). Sum 4 bytes per word, packed.
        int y = t - 256;
        uint32_t acc = 0u;
        const uint32_t* row = img + (y << 6);
        for (int j = 0; j < 64; ++j) {
            uint32_t w = row[(j + lane) & 63];
            acc += (w & 0x00FF00FFu) + ((w >> 8) & 0x00FF00FFu);
        }
        histY[(size_t)(b * SS + s) * 256 + y] = (acc & 0xFFFFu) + (acc >> 16);
    }
    __syncthreads();
    if (t < 64) {
        uint32_t s02 = xpart[0][t][0] + xpart[1][t][0]
                     + xpart[2][t][0] + xpart[3][t][0];
        uint32_t s13 = xpart[0][t][1] + xpart[1][t][1]
                     + xpart[2][t][1] + xpart[3][t][1];
        uint32_t* o = histX + (size_t)(b * SS + s) * 256 + (t << 2);
        o[0] = s02 & 0xFFFFu;
        o[1] = s13 & 0xFFFFu;
        o[2] = s02 >> 16;
        o[3] = s13 >> 16;
    }
}

// ---------------- K2: wave-parallel stats -> clip -> blur -> centroid -> shifts
__global__ __launch_bounds__(256) void k_shifts(const uint32_t* __restrict__ histX,
                                                const uint32_t* __restrict__ histY,
                                                const float* __restrict__ blurk,
                                                int* __restrict__ alignedX,
                                                int* __restrict__ alignedY) {
    int blk = blockIdx.x;          // 0..31 : b*2 + axis
    int b = blk >> 1, axis = blk & 1;
    const uint32_t* hist = (axis == 0 ? histX : histY) + (size_t)b * SS * DIM;
    int* out = (axis == 0 ? alignedX : alignedY) + b * SS;

    __shared__ float vals[SS][DIM];
    __shared__ double wsq[4];
    __shared__ float mrow[SS];
    int t = threadIdx.x;
    int w = t >> 6, lane = t & 63;
    int c0 = lane << 2;                       // 4 columns per lane

    double lsq = 0.0;
    for (int r = w; r < SS; r += 4) {
        uint4 u = *(const uint4*)(hist + r * DIM + c0);
        float v0 = (float)u.x, v1 = (float)u.y, v2 = (float)u.z, v3 = (float)u.w;
        vals[r][c0 + 0] = v0; vals[r][c0 + 1] = v1;
        vals[r][c0 + 2] = v2; vals[r][c0 + 3] = v3;
        double d0 = (double)v0 - 128.0, d1 = (double)v1 - 128.0;
        double d2 = (double)v2 - 128.0, d3 = (double)v3 - 128.0;
        lsq += d0 * d0 + d1 * d1 + d2 * d2 + d3 * d3;
    }
    for (int o = 32; o > 0; o >>= 1) lsq += __shfl_xor(lsq, o, 64);
    if (lane == 0) wsq[w] = lsq;
    __syncthreads();
    float s2 = (float)(wsq[0] + wsq[1] + wsq[2] + wsq[3]);   // exact integer
    float sd = sqrtf(s2 / 8191.0f);                          // ddof=1, pooled
    float thr = 128.0f + 3.0f * sd;

    float k00 = blurk[0], k01 = blurk[1], k02 = blurk[2];
    float k10 = blurk[3], k11 = blurk[4], k12 = blurk[5];
    float k20 = blurk[6], k21 = blurk[7], k22 = blurk[8];

#define V(r, c) fminf(vals[r][c], thr)
    for (int s = w; s < SS; s += 4) {
        double dot = 0.0;
#pragma unroll
        for (int j = 0; j < 4; ++j) {
            int c = c0 + j;
            int cm = c - 1, cp = c + 1;
            bool cml = (cm >= 0), cpl = (cp < DIM);
            float bsum = 0.0f;
            if (s - 1 >= 0) {
                if (cml) bsum += k00 * V(s - 1, cm);
                bsum += k01 * V(s - 1, c);
                if (cpl) bsum += k02 * V(s - 1, cp);
            }
            if (cml) bsum += k10 * V(s, cm);
            bsum += k11 * V(s, c);
            if (cpl) bsum += k12 * V(s, cp);
            if (s + 1 < SS) {
                if (cml) bsum += k20 * V(s + 1, cm);
                bsum += k21 * V(s + 1, c);
                if (cpl) bsum += k22 * V(s + 1, cp);
            }
            dot += (double)bsum * (double)c;
        }
        for (int o = 32; o > 0; o >>= 1) dot += __shfl_xor(dot, o, 64);
        if (lane == 0) mrow[s] = (float)(dot / 32768.0);
    }
#undef V
    __syncthreads();

    if (t < SS) {
        float start = mrow[2];                    // START = 2
        float a = mrow[t] - start;
        float c = 128.0f - start;                 // dimlen//2 - start
        out[t] = (int)rintf(a - c);               // round half-to-even
    }
}

// ---------------- K3: partial verifier bitmaps, group 0 (segs 2..9, 2 parts) ---
__global__ __launch_bounds__(256) void k_bitmap_g(const int* __restrict__ xs,
                                                  const int* __restrict__ ys,
                                                  const int* __restrict__ aX,
                                                  const int* __restrict__ aY,
                                                  uint32_t* __restrict__ bmp,
                                                  int first_seg, int nseg,
                                                  int parts) {
    int blk = blockIdx.x;
    int p = blk % parts;
    int sl = (blk / parts) % nseg;
    int b = blk / (parts * nseg);
    int s = first_seg + sl;
    int shx = aX[b * SS + s];
    int shy = aY[b * SS + s];
    __shared__ uint32_t bm[VW];
    int t = threadIdx.x;
    bm[t] = 0u; bm[t + 256] = 0u;
    __syncthreads();
    size_t base = (size_t)b * NTOT + (size_t)s * SEG + (size_t)p * (SEG / parts);
    const int4* x4 = (const int4*)(xs + base);
    const int4* y4 = (const int4*)(ys + base);
    int iters = SEG / (parts * 1024);
    for (int i = 0; i < iters; ++i) {
        int4 xv = x4[i * 256 + t];
        int4 yv = y4[i * 256 + t];
#define DOV(xc, yc) { int xf = clamp255((xc) - shx); int yf = clamp255((yc) - shy); \
                      int iv = (xf >> 1) + ((yf >> 1) << 7); \
                      atomicOr(&bm[iv >> 5], 1u << (iv & 31)); }
        DOV(xv.x, yv.x) DOV(xv.y, yv.y) DOV(xv.z, yv.z) DOV(xv.w, yv.w)
#undef DOV
    }
    __syncthreads();
    uint32_t* outp = bmp + ((size_t)(b * nseg + sl) * parts + p) * VW;
    outp[t] = bm[t];
    outp[t + 256] = bm[t + 256];
}

// ---------------- K4: sequential verifier scan, group 0 ------------------------
__global__ __launch_bounds__(256) void k_scan_g(const uint32_t* __restrict__ bmp,
                                                int* __restrict__ proceed,
                                                uint32_t* __restrict__ ver_state,
                                                int* __restrict__ total_state,
                                                int* __restrict__ active_state,
                                                int first_seg, int nseg,
                                                int parts) {
    int b = blockIdx.x;                   // 0..15
    int t = threadIdx.x;
    __shared__ uint32_t ver[VW];
    __shared__ int wred[4];
    __shared__ int sh_flag;
    __shared__ int sh_total;

    for (int i = t; i < nseg; i += 256) proceed[b * SS + first_seg + i] = 0;
    int active = 1;

    const uint32_t* base = bmp + (size_t)b * nseg * parts * VW;
    int wid = t >> 6, lane = t & 63;

    {
        uint32_t w0 = 0, w1 = 0;
        for (int p = 0; p < parts; ++p) {
            w0 |= base[(size_t)p * VW + t];
            w1 |= base[(size_t)p * VW + t + 256];
        }
        ver[t] = w0; ver[t + 256] = w1;
        int c = __popc(w0) + __popc(w1);
        for (int o = 32; o > 0; o >>= 1) c += __shfl_down(c, o, 64);
        if (lane == 0) wred[wid] = c;
        __syncthreads();
        if (t == 0) {
            sh_total = wred[0] + wred[1] + wred[2] + wred[3];
            proceed[b * SS + first_seg] = 1;   // START segment
        }
    }
    __syncthreads();

    for (int sl = 1; sl < nseg; ++sl) {
        uint32_t w0 = 0, w1 = 0;
        for (int p = 0; p < parts; ++p) {
            w0 |= base[(size_t)(sl * parts + p) * VW + t];
            w1 |= base[(size_t)(sl * parts + p) * VW + t + 256];
        }
        int c = __popc(w0 & ~ver[t]) + __popc(w1 & ~ver[t + 256]);
        for (int o = 32; o > 0; o >>= 1) c += __shfl_down(c, o, 64);
        if (lane == 0) wred[wid] = c;
        __syncthreads();
        if (t == 0) {
            int newly = wred[0] + wred[1] + wred[2] + wred[3];
            int total = sh_total + newly;
            float ratio = (float)newly / (float)total;
            int f = (ratio >= 0.01f) ? 1 : 0;
            sh_flag = f;
            if (f) {
                sh_total = total;
                proceed[b * SS + first_seg + sl] = 1;
            }
        }
        __syncthreads();
        if (!sh_flag) { active = 0; break; }
        ver[t] |= w0;
        ver[t + 256] |= w1;
        __syncthreads();
    }

    ver_state[(size_t)b * VW + t] = ver[t];
    ver_state[(size_t)b * VW + t + 256] = ver[t + 256];
    if (t == 0) {
        total_state[b] = sh_total;
        active_state[b] = active;
    }
}

// ---------------- K5: gated tail — bitmap+scan for segs 10..31, fused ----------
// 16 blocks. Expected: all batches inactive -> immediate return. Slow but
// correct serial fallback otherwise.
__global__ __launch_bounds__(256) void k_tail(const int* __restrict__ xs,
                                              const int* __restrict__ ys,
                                              const int* __restrict__ aX,
                                              const int* __restrict__ aY,
                                              int* __restrict__ proceed,
                                              const uint32_t* __restrict__ ver_state,
                                              const int* __restrict__ total_state,
                                              const int* __restrict__ active_state) {
    int b = blockIdx.x;
    int t = threadIdx.x;
    for (int i = t; i < SS - 10; i += 256) proceed[b * SS + 10 + i] = 0;
    if (!active_state[b]) return;

    __shared__ uint32_t ver[VW];
    __shared__ uint32_t bm[VW];
    __shared__ int wred[4];
    __shared__ int sh_flag;
    __shared__ int sh_total;
    ver[t] = ver_state[(size_t)b * VW + t];
    ver[t + 256] = ver_state[(size_t)b * VW + t + 256];
    if (t == 0) sh_total = total_state[b];
    int wid = t >> 6, lane = t & 63;
    __syncthreads();

    for (int s = 10; s < SS; ++s) {
        int shx = aX[b * SS + s];
        int shy = aY[b * SS + s];
        bm[t] = 0u; bm[t + 256] = 0u;
        __syncthreads();
        const int4* x4 = (const int4*)(xs + (size_t)b * NTOT + (size_t)s * SEG);
        const int4* y4 = (const int4*)(ys + (size_t)b * NTOT + (size_t)s * SEG);
        for (int i = 0; i < 32; ++i) {
            int4 xv = x4[i * 256 + t];
            int4 yv = y4[i * 256 + t];
#define DOV(xc, yc) { int xf = clamp255((xc) - shx); int yf = clamp255((yc) - shy); \
                      int iv = (xf >> 1) + ((yf >> 1) << 7); \
                      atomicOr(&bm[iv >> 5], 1u << (iv & 31)); }
            DOV(xv.x, yv.x) DOV(xv.y, yv.y) DOV(xv.z, yv.z) DOV(xv.w, yv.w)
#undef DOV
        }
        __syncthreads();
        uint32_t w0 = bm[t], w1 = bm[t + 256];
        int c = __popc(w0 & ~ver[t]) + __popc(w1 & ~ver[t + 256]);
        for (int o = 32; o > 0; o >>= 1) c += __shfl_down(c, o, 64);
        if (lane == 0) wred[wid] = c;
        __syncthreads();
        if (t == 0) {
            int newly = wred[0] + wred[1] + wred[2] + wred[3];
            int total = sh_total + newly;
            float ratio = (float)newly / (float)total;
            int f = (ratio >= 0.01f) ? 1 : 0;
            sh_flag = f;
            if (f) {
                sh_total = total;
                proceed[b * SS + s] = 1;
            }
        }
        __syncthreads();
        if (!sh_flag) break;
        ver[t] |= w0;
        ver[t + 256] |= w1;
        __syncthreads();
    }
}

// ---------------- K6: (b, half, eighth) LDS accumulation + sparse merge --------
__global__ __launch_bounds__(1024) void k_accum7(const int* __restrict__ xs,
                                                 const int* __restrict__ ys,
                                                 const int* __restrict__ aX,
                                                 const int* __restrict__ aY,
                                                 const int* __restrict__ proceed,
                                                 uint32_t* __restrict__ staging) {
    int blk = blockIdx.x;
    int p = blk & 7, half = (blk >> 3) & 1, b = blk >> 4;
    __shared__ uint32_t acc[16384];                   // 32768 u16 cells (128x256)
    int t = threadIdx.x;
    for (int i = t; i < 16384; i += 1024) acc[i] = 0u;
    __syncthreads();
    int ybase = half << 7;
    for (int s = 2; s < SS; ++s) {
        if (!proceed[b * SS + s]) continue;
        int shx = aX[b * SS + s];
        int shy = aY[b * SS + s];
        size_t base = (size_t)b * NTOT + (size_t)s * SEG + (size_t)p * 4096;
        int4 xv = ((const int4*)(xs + base))[t];
        int4 yv = ((const int4*)(ys + base))[t];
#define DOC(xc, yc) { int xf = clamp255((xc) - shx); int yf = clamp255((yc) - shy); \
                      if ((yf >> 7) == half) { \
                          int cell = xf + ((yf - ybase) << 8); \
                          atomicAdd(&acc[cell >> 1], 1u << ((cell & 1) << 4)); } }
        DOC(xv.x, yv.x) DOC(xv.y, yv.y) DOC(xv.z, yv.z) DOC(xv.w, yv.w)
#undef DOC
    }
    __syncthreads();
    uint32_t* stg = staging + (size_t)b * 32768 + ((size_t)half << 14);
    for (int i = t; i < 16384; i += 1024) {
        uint32_t w = acc[i];
        if (w) atomicAdd(&stg[i], w);     // packed u16 pair: no cross-carry
    }
}

// ---------------- K7: staging (packed u16) -> float output ---------------------
__global__ __launch_bounds__(1024) void k_convert(const uint32_t* __restrict__ staging,
                                                  float* __restrict__ out) {
    int g = blockIdx.x * 1024 + threadIdx.x;          // 0..524287
    uint32_t w = staging[g];
    ((float2*)out)[g] = make_float2((float)(w & 0xFFFFu), (float)(w >> 16));
}

extern "C" void kernel_launch(void* const* d_in, const int* in_sizes, int n_in,
                              void* d_out, int out_size, void* d_ws, size_t ws_size,
                              hipStream_t stream) {
    const int* xs = (const int*)d_in[0];
    const int* ys = (const int*)d_in[1];
    const float* blurk = (const float*)d_in[2];
    float* out = (float*)d_out;

    uint8_t* ws = (uint8_t*)d_ws;
    uint32_t* histX = (uint32_t*)(ws + OFF_HX);
    uint32_t* histY = (uint32_t*)(ws + OFF_HY);
    int* aX = (int*)(ws + OFF_AX);
    int* aY = (int*)(ws + OFF_AY);
    int* proceed = (int*)(ws + OFF_PR);
    int* active = (int*)(ws + OFF_ACT);
    int* total = (int*)(ws + OFF_TOT);
    uint32_t* ver = (uint32_t*)(ws + OFF_VER);
    uint32_t* bm0 = (uint32_t*)(ws + OFF_BM0);
    uint32_t* staging = (uint32_t*)(ws + OFF_STG);

    k_img<<<BB * SS, 512, 0, stream>>>(xs, ys, histX, histY, staging);
    k_shifts<<<BB * 2, 256, 0, stream>>>(histX, histY, blurk, aX, aY);

    // group 0: segments 2..9, 2 partials
    k_bitmap_g<<<BB * 8 * 2, 256, 0, stream>>>(xs, ys, aX, aY, bm0, 2, 8, 2);
    k_scan_g<<<BB, 256, 0, stream>>>(bm0, proceed, ver, total, active, 2, 8, 2);

    // gated tail: segments 10..31 fused bitmap+scan (expected immediate return)
    k_tail<<<BB, 256, 0, stream>>>(xs, ys, aX, aY, proceed, ver, total, active);

    k_accum7<<<BB * 2 * 8, 1024, 0, stream>>>(xs, ys, aX, aY, proceed, staging);
    k_convert<<<512, 1024, 0, stream>>>(staging, out);
}

// Round 13
// 65.956 us; speedup vs baseline: 1.1438x; 1.1438x over previous
//
#include <hip/hip_runtime.h>
#include <cstdint>
#include <cstddef>

#define BB 16
#define NTOT 1048576
#define SS 32
#define SEG 32768
#define DIM 256
#define VW 512        // verifier bitmap words (16384 bits)

// ---------------- workspace layout (bytes), sizes derived explicitly ----------
// histX : BB*SS*256*4 = 524,288        [0, 524288)
// histY : 524,288                      [524288, 1048576)
// BM0   : 16*8segs*2parts*512*4 = 1,048,576  [1048576, 2097152)
// AX/AY/PR small                       [2097152 ..)
// STG   : 2,097,152                    [2138112, 4235264) packed-u16 image
#define OFF_HX   0u
#define OFF_HY   524288u
#define OFF_BM0  1048576u
#define OFF_AX   2097152u            // BB*SS*4 = 2048
#define OFF_AY   2099200u            // 2048
#define OFF_PR   2101248u            // 2048
#define OFF_STG  2138112u            // 2 MB -> end 4,235,264 (~4.04 MB)

__device__ __forceinline__ int clamp255(int v) {
    return v < 0 ? 0 : (v > 255 ? 255 : v);
}

// ---------------- K1: conflict-free column histograms (LDS scatter wall) -------
// grid = BB*SS*2arr = 1024 blocks x 256 thr. ph[256][32], column = t&31 ->
// bank = t%32, data-independent. MEASURED WALL (rounds 4-12): ~42 us for the
// full 33.5M-update histogram regardless of mechanism (atomic / byte-RMW /
// 2D-pair-image) — structural floor. Also zeros the staging buffer.
__global__ __launch_bounds__(256) void k_hist4(const int* __restrict__ xs,
                                               const int* __restrict__ ys,
                                               uint32_t* __restrict__ histX,
                                               uint32_t* __restrict__ histY,
                                               uint32_t* __restrict__ staging) {
    int blk = blockIdx.x;
    int arr = blk & 1;
    int s = (blk >> 1) & 31;
    int b = blk >> 6;
    int t = threadIdx.x;
    // zero staging: 1024 blocks x 512 words = 2 MB
    staging[(size_t)blk * 512 + t] = 0u;
    staging[(size_t)blk * 512 + 256 + t] = 0u;

    const int* src = arr ? ys : xs;
    uint32_t* dst = arr ? histY : histX;
    __shared__ uint32_t ph[256][32];      // 32 KB
    uint32_t* phl = (uint32_t*)ph;
#pragma unroll
    for (int i = 0; i < 32; ++i) phl[t + i * 256] = 0u;   // bank t%32, free
    __syncthreads();
    int c = t & 31;
    const int4* p4 = (const int4*)(src + (size_t)b * NTOT + (size_t)s * SEG);
#pragma unroll 8
    for (int i = 0; i < 32; ++i) {        // 32 * 256 * 4 = 32768 elements
        int4 v = p4[i * 256 + t];
        atomicAdd(&ph[v.x][c], 1u);
        atomicAdd(&ph[v.y][c], 1u);
        atomicAdd(&ph[v.z][c], 1u);
        atomicAdd(&ph[v.w][c], 1u);
    }
    __syncthreads();
    uint32_t sum = 0u;
#pragma unroll
    for (int j = 0; j < 32; ++j)
        sum += ph[t][(j + t) & 31];       // rotated read, conflict-free
    dst[(size_t)(b * SS + s) * 256 + t] = sum;
}

// ---------------- K2: wave-parallel stats -> clip -> blur -> centroid -> shifts
// 32 blocks (b,axis) x 512 thr (8 waves): 4 rows/wave (halved serial chains
// vs 256-thr version). Pooled std (mean=128 exact, divisor 8191). Clip folded
// into blur reads (exact).
__global__ __launch_bounds__(512) void k_shifts(const uint32_t* __restrict__ histX,
                                                const uint32_t* __restrict__ histY,
                                                const float* __restrict__ blurk,
                                                int* __restrict__ alignedX,
                                                int* __restrict__ alignedY) {
    int blk = blockIdx.x;          // 0..31 : b*2 + axis
    int b = blk >> 1, axis = blk & 1;
    const uint32_t* hist = (axis == 0 ? histX : histY) + (size_t)b * SS * DIM;
    int* out = (axis == 0 ? alignedX : alignedY) + b * SS;

    __shared__ float vals[SS][DIM];
    __shared__ double wsq[8];
    __shared__ float mrow[SS];
    int t = threadIdx.x;
    int w = t >> 6, lane = t & 63;
    int c0 = lane << 2;                       // 4 columns per lane

    double lsq = 0.0;
    for (int r = w; r < SS; r += 8) {
        uint4 u = *(const uint4*)(hist + r * DIM + c0);
        float v0 = (float)u.x, v1 = (float)u.y, v2 = (float)u.z, v3 = (float)u.w;
        vals[r][c0 + 0] = v0; vals[r][c0 + 1] = v1;
        vals[r][c0 + 2] = v2; vals[r][c0 + 3] = v3;
        double d0 = (double)v0 - 128.0, d1 = (double)v1 - 128.0;
        double d2 = (double)v2 - 128.0, d3 = (double)v3 - 128.0;
        lsq += d0 * d0 + d1 * d1 + d2 * d2 + d3 * d3;
    }
    for (int o = 32; o > 0; o >>= 1) lsq += __shfl_xor(lsq, o, 64);
    if (lane == 0) wsq[w] = lsq;
    __syncthreads();
    float s2 = (float)(wsq[0] + wsq[1] + wsq[2] + wsq[3]
                     + wsq[4] + wsq[5] + wsq[6] + wsq[7]);   // exact integer
    float sd = sqrtf(s2 / 8191.0f);                          // ddof=1, pooled
    float thr = 128.0f + 3.0f * sd;

    float k00 = blurk[0], k01 = blurk[1], k02 = blurk[2];
    float k10 = blurk[3], k11 = blurk[4], k12 = blurk[5];
    float k20 = blurk[6], k21 = blurk[7], k22 = blurk[8];

#define V(r, c) fminf(vals[r][c], thr)
    for (int s = w; s < SS; s += 8) {
        double dot = 0.0;
#pragma unroll
        for (int j = 0; j < 4; ++j) {
            int c = c0 + j;
            int cm = c - 1, cp = c + 1;
            bool cml = (cm >= 0), cpl = (cp < DIM);
            float bsum = 0.0f;
            if (s - 1 >= 0) {
                if (cml) bsum += k00 * V(s - 1, cm);
                bsum += k01 * V(s - 1, c);
                if (cpl) bsum += k02 * V(s - 1, cp);
            }
            if (cml) bsum += k10 * V(s, cm);
            bsum += k11 * V(s, c);
            if (cpl) bsum += k12 * V(s, cp);
            if (s + 1 < SS) {
                if (cml) bsum += k20 * V(s + 1, cm);
                bsum += k21 * V(s + 1, c);
                if (cpl) bsum += k22 * V(s + 1, cp);
            }
            dot += (double)bsum * (double)c;
        }
        for (int o = 32; o > 0; o >>= 1) dot += __shfl_xor(dot, o, 64);
        if (lane == 0) mrow[s] = (float)(dot / 32768.0);
    }
#undef V
    __syncthreads();

    if (t < SS) {
        float start = mrow[2];                    // START = 2
        float a = mrow[t] - start;
        float c = 128.0f - start;                 // dimlen//2 - start
        out[t] = (int)rintf(a - c);               // round half-to-even
    }
}

// ---------------- K3: partial verifier bitmaps, segs 2..9, 2 parts -------------
// grid = 16*8*2 = 256 blocks; each partial block writes its own VW-word bitmap.
__global__ __launch_bounds__(256) void k_bitmap_g(const int* __restrict__ xs,
                                                  const int* __restrict__ ys,
                                                  const int* __restrict__ aX,
                                                  const int* __restrict__ aY,
                                                  uint32_t* __restrict__ bmp) {
    int blk = blockIdx.x;
    int p = blk & 1;
    int sl = (blk >> 1) & 7;
    int b = blk >> 4;
    int s = 2 + sl;
    int shx = aX[b * SS + s];
    int shy = aY[b * SS + s];
    __shared__ uint32_t bm[VW];
    int t = threadIdx.x;
    bm[t] = 0u; bm[t + 256] = 0u;
    __syncthreads();
    size_t base = (size_t)b * NTOT + (size_t)s * SEG + (size_t)p * (SEG / 2);
    const int4* x4 = (const int4*)(xs + base);
    const int4* y4 = (const int4*)(ys + base);
    for (int i = 0; i < 16; ++i) {        // 16 * 256 * 4 = 16384 elements
        int4 xv = x4[i * 256 + t];
        int4 yv = y4[i * 256 + t];
#define DOV(xc, yc) { int xf = clamp255((xc) - shx); int yf = clamp255((yc) - shy); \
                      int iv = (xf >> 1) + ((yf >> 1) << 7); \
                      atomicOr(&bm[iv >> 5], 1u << (iv & 31)); }
        DOV(xv.x, yv.x) DOV(xv.y, yv.y) DOV(xv.z, yv.z) DOV(xv.w, yv.w)
#undef DOV
    }
    __syncthreads();
    uint32_t* outp = bmp + ((size_t)(b * 8 + sl) * 2 + p) * VW;
    outp[t] = bm[t];
    outp[t + 256] = bm[t + 256];
}

// ---------------- K4: fused scan (segs 2..9 from bitmaps) + serial tail --------
// 16 blocks x 256 thr. Phase A: sequential scan over precomputed group-0
// bitmaps. Phase B (only if still active after seg 9 — not expected on this
// data): inline bitmap+scan of segs 10..31, serial but correct.
__global__ __launch_bounds__(256) void k_scan_tail(const int* __restrict__ xs,
                                                   const int* __restrict__ ys,
                                                   const int* __restrict__ aX,
                                                   const int* __restrict__ aY,
                                                   const uint32_t* __restrict__ bmp,
                                                   int* __restrict__ proceed) {
    int b = blockIdx.x;                   // 0..15
    int t = threadIdx.x;
    __shared__ uint32_t ver[VW];
    __shared__ uint32_t bm[VW];
    __shared__ int wred[4];
    __shared__ int sh_flag;
    __shared__ int sh_total;

    for (int i = t; i < 30; i += 256) proceed[b * SS + 2 + i] = 0;
    int active = 1;
    const uint32_t* base = bmp + (size_t)b * 8 * 2 * VW;
    int wid = t >> 6, lane = t & 63;

    // ---- Phase A: seg 2 (init) ----
    {
        uint32_t w0 = base[t] | base[VW + t];
        uint32_t w1 = base[t + 256] | base[VW + t + 256];
        ver[t] = w0; ver[t + 256] = w1;
        int c = __popc(w0) + __popc(w1);
        for (int o = 32; o > 0; o >>= 1) c += __shfl_down(c, o, 64);
        if (lane == 0) wred[wid] = c;
        __syncthreads();
        if (t == 0) {
            sh_total = wred[0] + wred[1] + wred[2] + wred[3];
            proceed[b * SS + 2] = 1;      // START segment
        }
    }
    __syncthreads();

    // ---- Phase A: segs 3..9 ----
    for (int sl = 1; sl < 8; ++sl) {
        uint32_t w0 = base[(size_t)(sl * 2) * VW + t]
                    | base[(size_t)(sl * 2 + 1) * VW + t];
        uint32_t w1 = base[(size_t)(sl * 2) * VW + t + 256]
                    | base[(size_t)(sl * 2 + 1) * VW + t + 256];
        int c = __popc(w0 & ~ver[t]) + __popc(w1 & ~ver[t + 256]);
        for (int o = 32; o > 0; o >>= 1) c += __shfl_down(c, o, 64);
        if (lane == 0) wred[wid] = c;
        __syncthreads();
        if (t == 0) {
            int newly = wred[0] + wred[1] + wred[2] + wred[3];
            int total = sh_total + newly;
            float ratio = (float)newly / (float)total;
            int f = (ratio >= 0.01f) ? 1 : 0;
            sh_flag = f;
            if (f) {
                sh_total = total;
                proceed[b * SS + 2 + sl] = 1;
            }
        }
        __syncthreads();
        if (!sh_flag) { active = 0; break; }
        ver[t] |= w0;
        ver[t + 256] |= w1;
        __syncthreads();
    }
    if (!active) return;

    // ---- Phase B: serial tail, segs 10..31 (fallback; not expected) ----
    for (int s = 10; s < SS; ++s) {
        int shx = aX[b * SS + s];
        int shy = aY[b * SS + s];
        bm[t] = 0u; bm[t + 256] = 0u;
        __syncthreads();
        const int4* x4 = (const int4*)(xs + (size_t)b * NTOT + (size_t)s * SEG);
        const int4* y4 = (const int4*)(ys + (size_t)b * NTOT + (size_t)s * SEG);
        for (int i = 0; i < 32; ++i) {
            int4 xv = x4[i * 256 + t];
            int4 yv = y4[i * 256 + t];
#define DOV(xc, yc) { int xf = clamp255((xc) - shx); int yf = clamp255((yc) - shy); \
                      int iv = (xf >> 1) + ((yf >> 1) << 7); \
                      atomicOr(&bm[iv >> 5], 1u << (iv & 31)); }
            DOV(xv.x, yv.x) DOV(xv.y, yv.y) DOV(xv.z, yv.z) DOV(xv.w, yv.w)
#undef DOV
        }
        __syncthreads();
        uint32_t w0 = bm[t], w1 = bm[t + 256];
        int c = __popc(w0 & ~ver[t]) + __popc(w1 & ~ver[t + 256]);
        for (int o = 32; o > 0; o >>= 1) c += __shfl_down(c, o, 64);
        if (lane == 0) wred[wid] = c;
        __syncthreads();
        if (t == 0) {
            int newly = wred[0] + wred[1] + wred[2] + wred[3];
            int total = sh_total + newly;
            float ratio = (float)newly / (float)total;
            int f = (ratio >= 0.01f) ? 1 : 0;
            sh_flag = f;
            if (f) {
                sh_total = total;
                proceed[b * SS + s] = 1;
            }
        }
        __syncthreads();
        if (!sh_flag) break;
        ver[t] |= w0;
        ver[t + 256] |= w1;
        __syncthreads();
    }
}

// ---------------- K5: (b, half, eighth) LDS accumulation + sparse merge --------
// 256 blocks x 1024 thr -> 1 block/CU. Packed-u16 LDS y-half image; nonzero
// words atomicAdd'ed into staging (zeroed by k_hist4).
__global__ __launch_bounds__(1024) void k_accum7(const int* __restrict__ xs,
                                                 const int* __restrict__ ys,
                                                 const int* __restrict__ aX,
                                                 const int* __restrict__ aY,
                                                 const int* __restrict__ proceed,
                                                 uint32_t* __restrict__ staging) {
    int blk = blockIdx.x;
    int p = blk & 7, half = (blk >> 3) & 1, b = blk >> 4;
    __shared__ uint32_t acc[16384];                   // 32768 u16 cells (128x256)
    int t = threadIdx.x;
    for (int i = t; i < 16384; i += 1024) acc[i] = 0u;
    __syncthreads();
    int ybase = half << 7;
    for (int s = 2; s < SS; ++s) {
        if (!proceed[b * SS + s]) continue;
        int shx = aX[b * SS + s];
        int shy = aY[b * SS + s];
        size_t base = (size_t)b * NTOT + (size_t)s * SEG + (size_t)p * 4096;
        int4 xv = ((const int4*)(xs + base))[t];
        int4 yv = ((const int4*)(ys + base))[t];
#define DOC(xc, yc) { int xf = clamp255((xc) - shx); int yf = clamp255((yc) - shy); \
                      if ((yf >> 7) == half) { \
                          int cell = xf + ((yf - ybase) << 8); \
                          atomicAdd(&acc[cell >> 1], 1u << ((cell & 1) << 4)); } }
        DOC(xv.x, yv.x) DOC(xv.y, yv.y) DOC(xv.z, yv.z) DOC(xv.w, yv.w)
#undef DOC
    }
    __syncthreads();
    uint32_t* stg = staging + (size_t)b * 32768 + ((size_t)half << 14);
    for (int i = t; i < 16384; i += 1024) {
        uint32_t w = acc[i];
        if (w) atomicAdd(&stg[i], w);     // packed u16 pair: no cross-carry
    }
}

// ---------------- K6: staging (packed u16) -> float output ---------------------
__global__ __launch_bounds__(1024) void k_convert(const uint32_t* __restrict__ staging,
                                                  float* __restrict__ out) {
    int g = blockIdx.x * 1024 + threadIdx.x;          // 0..524287
    uint32_t w = staging[g];
    ((float2*)out)[g] = make_float2((float)(w & 0xFFFFu), (float)(w >> 16));
}

extern "C" void kernel_launch(void* const* d_in, const int* in_sizes, int n_in,
                              void* d_out, int out_size, void* d_ws, size_t ws_size,
                              hipStream_t stream) {
    const int* xs = (const int*)d_in[0];
    const int* ys = (const int*)d_in[1];
    const float* blurk = (const float*)d_in[2];
    float* out = (float*)d_out;

    uint8_t* ws = (uint8_t*)d_ws;
    uint32_t* histX = (uint32_t*)(ws + OFF_HX);
    uint32_t* histY = (uint32_t*)(ws + OFF_HY);
    int* aX = (int*)(ws + OFF_AX);
    int* aY = (int*)(ws + OFF_AY);
    int* proceed = (int*)(ws + OFF_PR);
    uint32_t* bm0 = (uint32_t*)(ws + OFF_BM0);
    uint32_t* staging = (uint32_t*)(ws + OFF_STG);

    k_hist4<<<BB * SS * 2, 256, 0, stream>>>(xs, ys, histX, histY, staging);
    k_shifts<<<BB * 2, 512, 0, stream>>>(histX, histY, blurk, aX, aY);
    k_bitmap_g<<<BB * 8 * 2, 256, 0, stream>>>(xs, ys, aX, aY, bm0);
    k_scan_tail<<<BB, 256, 0, stream>>>(xs, ys, aX, aY, bm0, proceed);
    k_accum7<<<BB * 2 * 8, 1024, 0, stream>>>(xs, ys, aX, aY, proceed, staging);
    k_convert<<<512, 1024, 0, stream>>>(staging, out);
}